// Round 14
// baseline (395.803 us; speedup 1.0000x reference)
//
#include <hip/hip_runtime.h>
#include <hip/hip_bf16.h>
#include <math.h>
#include <stdint.h>

typedef unsigned short u16;
typedef unsigned int u32;
typedef __attribute__((ext_vector_type(8))) short short8;
typedef __attribute__((ext_vector_type(4))) float f32x4;
typedef __attribute__((ext_vector_type(2))) float f32x2;

#define BN 256      // nodes per bucket (power of 2)
#define NBMAX 400   // max buckets (N<=102400)
#define EPB 4096    // edges per block in count/scatter
#define ST1 152     // staged edges per node, agg1 (keeps per-h union at 1216B+pad)
#define ST2 192     // staged edges per node, agg2

__device__ __forceinline__ u16 bfbits(float f) {
    __hip_bfloat16 h = __float2bfloat16(f);
    return *reinterpret_cast<u16*>(&h);
}
__device__ __forceinline__ float bflo(u32 v) { return __uint_as_float(v << 16); }
__device__ __forceinline__ float bfhi(u32 v) { return __uint_as_float(v & 0xffff0000u); }

template <bool HI>
__device__ __forceinline__ f32x2 fp8pair(u32 v) {
#if __has_builtin(__builtin_amdgcn_cvt_pk_f32_fp8)
    return __builtin_amdgcn_cvt_pk_f32_fp8(v, HI);
#else
    f32x2 r;
    r.x = __builtin_amdgcn_cvt_f32_fp8(v, HI ? 2 : 0);
    r.y = __builtin_amdgcn_cvt_f32_fp8(v, HI ? 3 : 1);
    return r;
#endif
}

__device__ __forceinline__ int sigma128(int col) {
    int a = col >> 6, c = (col >> 4) & 3, lr = col & 15;
    return (a << 6) + (lr << 2) + c;
}

// ---------------- FUSED: bucket counts | W1->bf16 swizzle | b1 sigma / W2^T sigma prep ----------------
__global__ __launch_bounds__(256) void k_pre(const int* __restrict__ ei, int E, int n, int nb,
                                             int nblkc, int* __restrict__ gcnt,
                                             const float* __restrict__ w1, short* __restrict__ w1bf,
                                             const float* __restrict__ b1, const float* __restrict__ w2,
                                             float* __restrict__ b1p, float* __restrict__ w2t) {
    __shared__ int sh[NBMAX];
    const int t = threadIdx.x;
    const int b = blockIdx.x;
    if (b < nblkc) {                           // ---- bucket count ----
        const int* col = ei + E;
        for (int i = t; i < nb; i += 256) sh[i] = 0;
        __syncthreads();
        const int base = b * EPB;
#pragma unroll
        for (int j = 0; j < 16; ++j) {
            int e = base + j * 256 + t;
            if (e < E) {
                unsigned c = (unsigned)col[e];
                if (c < (unsigned)n) atomicAdd(&sh[c >> 8], 1);
            }
        }
        __syncthreads();
        for (int i = t; i < nb; i += 256)
            if (sh[i]) atomicAdd(&gcnt[i], sh[i]);
    } else if (b < nblkc + 128) {              // ---- W1 swizzle (32768 elems) ----
        int i = (b - nblkc) * 256 + t;
        int e = i & 7, l = (i >> 3) & 63, kt = (i >> 9) & 7, ct = i >> 12;
        int k = kt * 32 + (l >> 4) * 8 + e;
        int c = ct * 16 + (l & 15);
        w1bf[i] = (short)bfbits(w1[(size_t)k * 128 + c]);
    } else {                                   // ---- b1 sigma permute | W2^T (sigma'd k) ----
        int i = (b - nblkc - 128) * 256 + t;
        if (i < 128) b1p[sigma128(i)] = b1[i];
        int j = i - 128;
        if (j >= 0 && j < 128 * 40) {
            int k = j / 40, c = j - k * 40;
            w2t[(size_t)c * 128 + sigma128(k)] = w2[j];
        }
    }
}

// ---------------- bucket scan (single block) ----------------
__global__ __launch_bounds__(512) void k_bscan(const int* __restrict__ gcnt,
                                               int* __restrict__ ebase, int* __restrict__ cursor,
                                               int* __restrict__ off, int nb, int n) {
    __shared__ int sh[512];
    const int t = threadIdx.x;
    int v = (t < nb) ? gcnt[t] : 0;
    sh[t] = v;
    __syncthreads();
    for (int d = 1; d < 512; d <<= 1) {
        int x = (t >= d) ? sh[t - d] : 0;
        __syncthreads();
        sh[t] += x;
        __syncthreads();
    }
    if (t < nb) {
        int excl = sh[t] - v;
        ebase[t] = excl;
        cursor[t] = excl;
    }
    if (t == 0) {
        ebase[nb] = sh[511];
        off[n] = sh[511] + n;
    }
}

// ---------------- FUSED: edge scatter | GEMM1 (LDS-staged x, streaming loads) ----------------
struct SMemScat { int cnt[NBMAX]; int cbase[NBMAX]; };
union SMemU {
    SMemScat s;
    u16 xt[64 * 128];   // 16KB: 64 rows x 128 bf16 (one k-half), XOR-swizzled
};

__global__ __launch_bounds__(256) void k_scatg1(const int* __restrict__ ei,
                                                int* __restrict__ cursor, u32* __restrict__ staging,
                                                int E, int n, int nb, int nblks,
                                                const float* __restrict__ x,
                                                const short* __restrict__ w1bf,
                                                u32* __restrict__ hbf8) {
    __shared__ SMemU sm;
    const int t = threadIdx.x;
    if ((int)blockIdx.x < nblks) {             // ---- scat ----
        for (int i = t; i < nb; i += 256) sm.s.cnt[i] = 0;
        __syncthreads();
        const int base = blockIdx.x * EPB;
        int rr[16], cc[16], rk[16];
#pragma unroll
        for (int j = 0; j < 16; ++j) {
            int e = base + j * 256 + t;
            cc[j] = -1;
            if (e < E) {
                unsigned r = (unsigned)ei[e], c = (unsigned)ei[E + e];
                if (r < (unsigned)n && c < (unsigned)n) {
                    rr[j] = (int)r;
                    cc[j] = (int)c;
                    rk[j] = atomicAdd(&sm.s.cnt[c >> 8], 1);
                }
            }
        }
        __syncthreads();
        for (int i = t; i < nb; i += 256)
            if (sm.s.cnt[i]) sm.s.cbase[i] = atomicAdd(&cursor[i], sm.s.cnt[i]);
        __syncthreads();
#pragma unroll
        for (int j = 0; j < 16; ++j) {
            if (cc[j] >= 0) {
                int b = cc[j] >> 8;
                staging[sm.s.cbase[b] + rk[j]] = (u32)rr[j] | ((u32)(cc[j] & (BN - 1)) << 17);
            }
        }
        return;
    }
    // ---- gemm1: stage x -> LDS (bf16, swizzled) in 2 k-halves; frags via ds_read ----
    const int bid = blockIdx.x - nblks;
    const int wv = t >> 6, l = t & 63;
    const int mrow = wv >> 1, mcol = wv & 1;
    const int lr = l & 15, kg = l >> 4;
    const int n0 = bid * 64;

    const short* bbase = w1bf + ((size_t)(4 * mcol) * 8) * 64 * 8 + (size_t)l * 8;

    f32x4 zero = {0.f, 0.f, 0.f, 0.f};
    f32x4 acc[2][4];
#pragma unroll
    for (int m = 0; m < 2; ++m)
#pragma unroll
        for (int c = 0; c < 4; ++c) acc[m][c] = zero;

#pragma unroll
    for (int p = 0; p < 2; ++p) {
        __syncthreads();
#pragma unroll
        for (int j = 0; j < 8; ++j) {
            int idx = j * 256 + t;
            int row = idx >> 5;
            int kf4 = idx & 31;
            int grow = n0 + row;
            if (grow > n - 1) grow = n - 1;
            float4 v = *(const float4*)(x + (size_t)grow * 256 + p * 128 + kf4 * 4);
            u32 w0 = (u32)bfbits(v.x) | ((u32)bfbits(v.y) << 16);
            u32 w1v = (u32)bfbits(v.z) | ((u32)bfbits(v.w) << 16);
            int bir = kf4 * 8;
            int sb = row * 256 + (bir ^ ((row & 7) << 4));
            *(uint2*)((char*)sm.xt + sb) = make_uint2(w0, w1v);
        }
        __syncthreads();
#pragma unroll
        for (int ktl = 0; ktl < 4; ++ktl) {
            int kt = p * 4 + ktl;
            short8 af[2];
#pragma unroll
            for (int m = 0; m < 2; ++m) {
                int r = 32 * mrow + 16 * m + lr;
                int bir = ktl * 64 + kg * 16;
                int sb = r * 256 + (bir ^ ((r & 7) << 4));
                af[m] = *(const short8*)((const char*)sm.xt + sb);
            }
#pragma unroll
            for (int c = 0; c < 4; ++c) {
                short8 bfrag = *(const short8*)(bbase + ((size_t)(c * 8 + kt) * 64) * 8);
#pragma unroll
                for (int m = 0; m < 2; ++m)
                    acc[m][c] = __builtin_amdgcn_mfma_f32_16x16x32_bf16(af[m], bfrag,
                                                                        acc[m][c], 0, 0, 0);
            }
        }
    }

#pragma unroll
    for (int m = 0; m < 2; ++m) {
        int rbase = n0 + 32 * mrow + 16 * m + kg * 4;
#pragma unroll
        for (int r = 0; r < 4; ++r) {
            int row = rbase + r;
            if (row < n) {
                int w = __builtin_amdgcn_cvt_pk_fp8_f32(acc[m][0][r], acc[m][1][r], 0, false);
                w = __builtin_amdgcn_cvt_pk_fp8_f32(acc[m][2][r], acc[m][3][r], w, true);
                hbf8[(size_t)row * 32 + 16 * mcol + lr] = (u32)w;
            }
        }
    }
}

// ---------------- per-bucket CSR build ----------------
__global__ __launch_bounds__(256) void k_build(const u32* __restrict__ staging,
                                               const int* __restrict__ ebase,
                                               int* __restrict__ csrs, int* __restrict__ off,
                                               float* __restrict__ dinv, int n) {
    __shared__ int sh[256];
    __shared__ int cur[256];
    const int t = threadIdx.x;
    const int b = blockIdx.x;
    const int e0 = ebase[b], e1 = ebase[b + 1];
    const int node0 = b * BN;
    const int nn = min(BN, n - node0);
    sh[t] = 0;
    __syncthreads();
    for (int i = e0 + t; i < e1; i += 256)
        atomicAdd(&sh[staging[i] >> 17], 1);
    __syncthreads();
    const int mycnt = sh[t];
    const int myval = (t < nn) ? mycnt + 1 : 0;
    sh[t] = myval;
    __syncthreads();
    for (int d = 1; d < 256; d <<= 1) {
        int x = (t >= d) ? sh[t - d] : 0;
        __syncthreads();
        sh[t] += x;
        __syncthreads();
    }
    const int excl = sh[t] - myval;
    const int csrbase = e0 + node0;
    if (t < nn) {
        int node = node0 + t;
        int o = csrbase + excl;
        off[node] = o;
        dinv[node] = rsqrtf((float)(mycnt + 1));
        csrs[o] = node;
        cur[t] = o + 1;
    }
    __syncthreads();
    for (int i = e0 + t; i < e1; i += 256) {
        u32 v = staging[i];
        int p = atomicAdd(&cur[v >> 17], 1);
        csrs[p] = (int)(v & 0x1FFFF);
    }
}

// ---------------- Agg1 + GEMM2 fused: h1 in LDS, h2 int8 out ----------------
// 2 nodes/wave, 32 lanes/node. Per-h LDS union: gather staging then h1/out epilogue.
struct AggH {
    union {
        struct { int s[ST1]; float f[ST1]; } g;       // 1216B
        struct { float h1[128]; float out[48]; } e;   // 704B
    };
    int pad[16];                                       // -> 1280B per h, 16B-aligned
};

__global__ __launch_bounds__(256) void k_agg1g2(const u32* __restrict__ hbf8,
                                                const int* __restrict__ off,
                                                const int* __restrict__ csrs,
                                                const float* __restrict__ dinv,
                                                const float* __restrict__ b1p,
                                                const float* __restrict__ w2t,
                                                u32* __restrict__ h2q, float* __restrict__ scl,
                                                int n) {
    __shared__ AggH sm[8];   // 10.25KB
    const int t = threadIdx.x, h = t >> 5, fl = t & 31;
    const int node = blockIdx.x * 8 + h;
    const int nd = node < n ? node : n - 1;
    const float dn = dinv[nd];
    const int e0 = off[nd], e1 = off[nd + 1];
    const int deg = e1 - e0;
    const int nst = deg < ST1 ? deg : ST1;
    for (int i = fl; i < nst; i += 32) {
        int s = csrs[e0 + i];
        sm[h].g.s[i] = s;
        sm[h].g.f[i] = dinv[s] * dn;
    }
    __syncthreads();

    const int onst = __shfl_xor(nst, 32, 64);
    const int nmin = nst < onst ? nst : onst;
    const int nmax = nst > onst ? nst : onst;
    const int odeg = __shfl_xor(deg, 32, 64);
    const int dmax = deg > odeg ? deg : odeg;

    const u32* hb = hbf8;
    float a0 = 0.f, a1 = 0.f, a2 = 0.f, a3 = 0.f;
    int i = 0;
    for (; i + 16 <= nmin; i += 16) {
        u32 vv[16];
        float ww[16];
#pragma unroll
        for (int k = 0; k < 16; ++k) {
            int s = sm[h].g.s[i + k];
            ww[k] = sm[h].g.f[i + k];
            vv[k] = hb[(size_t)s * 32 + fl];
        }
#pragma unroll
        for (int k = 0; k < 16; ++k) {
            f32x2 lo = fp8pair<false>(vv[k]), hi = fp8pair<true>(vv[k]);
            a0 = fmaf(lo.x, ww[k], a0); a1 = fmaf(lo.y, ww[k], a1);
            a2 = fmaf(hi.x, ww[k], a2); a3 = fmaf(hi.y, ww[k], a3);
        }
    }
    for (; i + 4 <= nmin; i += 4) {
        u32 vv[4];
        float ww[4];
#pragma unroll
        for (int k = 0; k < 4; ++k) {
            int s = sm[h].g.s[i + k];
            ww[k] = sm[h].g.f[i + k];
            vv[k] = hb[(size_t)s * 32 + fl];
        }
#pragma unroll
        for (int k = 0; k < 4; ++k) {
            f32x2 lo = fp8pair<false>(vv[k]), hi = fp8pair<true>(vv[k]);
            a0 = fmaf(lo.x, ww[k], a0); a1 = fmaf(lo.y, ww[k], a1);
            a2 = fmaf(hi.x, ww[k], a2); a3 = fmaf(hi.y, ww[k], a3);
        }
    }
    for (; i < nmin; ++i) {
        int s = sm[h].g.s[i];
        float w = sm[h].g.f[i];
        u32 v = hb[(size_t)s * 32 + fl];
        f32x2 lo = fp8pair<false>(v), hi = fp8pair<true>(v);
        a0 = fmaf(lo.x, w, a0); a1 = fmaf(lo.y, w, a1);
        a2 = fmaf(hi.x, w, a2); a3 = fmaf(hi.y, w, a3);
    }
    for (; i < nmax; ++i) {
        bool ok = i < nst;
        int s = ok ? sm[h].g.s[i] : nd;
        float w = ok ? sm[h].g.f[i] : 0.f;
        u32 v = hb[(size_t)s * 32 + fl];
        f32x2 lo = fp8pair<false>(v), hi = fp8pair<true>(v);
        a0 = fmaf(lo.x, w, a0); a1 = fmaf(lo.y, w, a1);
        a2 = fmaf(hi.x, w, a2); a3 = fmaf(hi.y, w, a3);
    }
    for (int j = ST1; j < dmax; ++j) {
        bool ok = j < deg;
        int s = ok ? csrs[e0 + j] : nd;
        float w = ok ? dinv[s] * dn : 0.f;
        u32 v = hb[(size_t)s * 32 + fl];
        f32x2 lo = fp8pair<false>(v), hi = fp8pair<true>(v);
        a0 = fmaf(lo.x, w, a0); a1 = fmaf(lo.y, w, a1);
        a2 = fmaf(hi.x, w, a2); a3 = fmaf(hi.y, w, a3);
    }

    // h1 row (f32, sigma order): relu(acc + b1p)
    float4 bb = *(const float4*)(b1p + 4 * fl);
    float r0 = fmaxf(a0 + bb.x, 0.f);
    float r1 = fmaxf(a1 + bb.y, 0.f);
    float r2 = fmaxf(a2 + bb.z, 0.f);
    float r3 = fmaxf(a3 + bb.w, 0.f);
    // gather staging for this half-wave is dead; reuse as h1 buffer (same-wave LDS order)
    *(float4*)&sm[h].e.h1[4 * fl] = make_float4(r0, r1, r2, r3);

    // ---- fused GEMM2: outputs c1 = fl, c2 = 32+fl (fl<8) ----
    const int c2 = (fl < 8) ? 32 + fl : 39;
    const float* w2r1 = w2t + (size_t)fl * 128;
    const float* w2r2 = w2t + (size_t)c2 * 128;
    float acc1 = 0.f, acc2 = 0.f;
#pragma unroll
    for (int kk = 0; kk < 32; ++kk) {
        float4 hv = *(const float4*)&sm[h].e.h1[4 * kk];   // LDS broadcast
        float4 wa = *(const float4*)(w2r1 + 4 * kk);
        float4 wb = *(const float4*)(w2r2 + 4 * kk);
        acc1 = fmaf(hv.x, wa.x, acc1); acc1 = fmaf(hv.y, wa.y, acc1);
        acc1 = fmaf(hv.z, wa.z, acc1); acc1 = fmaf(hv.w, wa.w, acc1);
        acc2 = fmaf(hv.x, wb.x, acc2); acc2 = fmaf(hv.y, wb.y, acc2);
        acc2 = fmaf(hv.z, wb.z, acc2); acc2 = fmaf(hv.w, wb.w, acc2);
    }
    sm[h].e.out[fl] = acc1;
    if (fl < 8) sm[h].e.out[32 + fl] = acc2;

    float m = fabsf(acc1);
    if (fl < 8) m = fmaxf(m, fabsf(acc2));
#pragma unroll
    for (int d = 16; d > 0; d >>= 1) m = fmaxf(m, __shfl_xor(m, d, 32));
    const float qs = m > 0.f ? 127.f / m : 0.f;

    if (node < n) {
        if (fl < 16) {
            u32 w = 0;
            if (fl < 10) {
#pragma unroll
                for (int k = 0; k < 4; ++k) {
                    float v = sm[h].e.out[4 * fl + k];
                    int q = __float2int_rn(v * qs);
                    q = q > 127 ? 127 : (q < -127 ? -127 : q);
                    w |= ((u32)(q & 255)) << (8 * k);
                }
            }
            h2q[(size_t)node * 16 + fl] = w;
        }
        if (fl == 0) scl[node] = m * (1.f / 127.f);
    }
}

// ---------------- Agg2 (int8 gather) + bias + log_softmax ----------------
__global__ __launch_bounds__(256) void k_agg2(const u32* __restrict__ h2q,
                                              const float* __restrict__ scl,
                                              const int* __restrict__ off,
                                              const int* __restrict__ csrs,
                                              const float* __restrict__ dinv,
                                              const float* __restrict__ b2,
                                              float* __restrict__ out, int n) {
    __shared__ int s_s[4][ST2];
    __shared__ float s_f[4][ST2];
    const int t = threadIdx.x, wv = t >> 6, l = t & 63;
    const int node = blockIdx.x * 4 + wv;
    const int nd = node < n ? node : n - 1;
    const float dn = dinv[nd];
    const int e0 = off[nd], e1 = off[nd + 1];
    const int deg = e1 - e0;
    const int nst = deg < ST2 ? deg : ST2;
    for (int i = l; i < nst; i += 64) {
        int s = csrs[e0 + i];
        s_s[wv][i] = s;
        s_f[wv][i] = dinv[s] * dn * scl[s];
    }
    __syncthreads();

    const int g = l >> 4;
    const int fl = l & 15;

#define ACC4(v, w)                                                         \
    {                                                                      \
        a0 = fmaf((float)(int)(signed char)((v) & 0xff), (w), a0);         \
        a1 = fmaf((float)(int)(signed char)(((v) >> 8) & 0xff), (w), a1);  \
        a2 = fmaf((float)(int)(signed char)(((v) >> 16) & 0xff), (w), a2); \
        a3 = fmaf((float)(int)(signed char)((v) >> 24), (w), a3);          \
    }

    float a0 = 0.f, a1 = 0.f, a2 = 0.f, a3 = 0.f;
    int base = 0;
    for (; base + 16 <= nst; base += 16) {
        int eA = base + g, eB = base + 4 + g, eC = base + 8 + g, eD = base + 12 + g;
        int sA = s_s[wv][eA], sB = s_s[wv][eB], sC = s_s[wv][eC], sD = s_s[wv][eD];
        float wA = s_f[wv][eA], wB = s_f[wv][eB], wC = s_f[wv][eC], wD = s_f[wv][eD];
        u32 vA = h2q[(size_t)sA * 16 + fl];
        u32 vB = h2q[(size_t)sB * 16 + fl];
        u32 vC = h2q[(size_t)sC * 16 + fl];
        u32 vD = h2q[(size_t)sD * 16 + fl];
        ACC4(vA, wA); ACC4(vB, wB); ACC4(vC, wC); ACC4(vD, wD);
    }
    for (; base < nst; base += 4) {
        int e = base + g;
        bool ok = e < nst;
        int s = ok ? s_s[wv][e] : nd;
        float w = ok ? s_f[wv][e] : 0.f;
        u32 v = h2q[(size_t)s * 16 + fl];
        ACC4(v, w);
    }
    for (int j = nst; j < deg; j += 4) {
        int e = j + g;
        bool ok = e < deg;
        int s = ok ? csrs[e0 + e] : nd;
        float w = ok ? dinv[s] * dn * scl[s] : 0.f;
        u32 v = h2q[(size_t)s * 16 + fl];
        ACC4(v, w);
    }
#undef ACC4

    float t0 = __shfl(a0, (l + 32) & 63, 64);
    float t1 = __shfl(a1, (l + 32) & 63, 64);
    float t2 = __shfl(a2, (l + 32) & 63, 64);
    float t3 = __shfl(a3, (l + 32) & 63, 64);
    a0 += t0; a1 += t1; a2 += t2; a3 += t3;
    t0 = __shfl(a0, (l + 16) & 63, 64);
    t1 = __shfl(a1, (l + 16) & 63, 64);
    t2 = __shfl(a2, (l + 16) & 63, 64);
    t3 = __shfl(a3, (l + 16) & 63, 64);
    a0 += t0; a1 += t1; a2 += t2; a3 += t3;

    const bool act = (l < 10);
    float4 bb = *(const float4*)(b2 + 4 * (act ? l : 9));
    float v0 = a0 + bb.x, v1 = a1 + bb.y, v2 = a2 + bb.z, v3 = a3 + bb.w;

    float m = act ? fmaxf(fmaxf(v0, v1), fmaxf(v2, v3)) : -INFINITY;
#pragma unroll
    for (int d = 8; d > 0; d >>= 1) m = fmaxf(m, __shfl_xor(m, d, 16));
    float s = act ? (__expf(v0 - m) + __expf(v1 - m) + __expf(v2 - m) + __expf(v3 - m)) : 0.f;
#pragma unroll
    for (int d = 8; d > 0; d >>= 1) s += __shfl_xor(s, d, 16);
    float ls = logf(s);
    if (node < n && act) {
        float4 o = make_float4(v0 - m - ls, v1 - m - ls, v2 - m - ls, v3 - m - ls);
        *(float4*)(out + (size_t)node * 40 + 4 * l) = o;
    }
}

extern "C" void kernel_launch(void* const* d_in, const int* in_sizes, int n_in,
                              void* d_out, int out_size, void* d_ws, size_t ws_size,
                              hipStream_t stream) {
    const float* x = (const float*)d_in[0];
    const int* ei = (const int*)d_in[1];
    const float* w1 = (const float*)d_in[2];
    const float* b1 = (const float*)d_in[3];
    const float* w2 = (const float*)d_in[4];
    const float* b2 = (const float*)d_in[5];
    float* out = (float*)d_out;

    const int N = in_sizes[0] / 256;
    const int E = in_sizes[1] / 2;
    const int NB = (N + BN - 1) / BN;

    char* p = (char*)d_ws;
    auto alloc = [&](size_t bytes) {
        char* r = p;
        p += (bytes + 255) & ~(size_t)255;
        return r;
    };
    int* gcnt = (int*)alloc((size_t)NB * 4);
    int* ebase = (int*)alloc((size_t)(NB + 1) * 4);
    int* cursor = (int*)alloc((size_t)NB * 4);
    int* off = (int*)alloc((size_t)(N + 1) * 4);
    float* dinv = (float*)alloc((size_t)N * 4);
    float* scl = (float*)alloc((size_t)N * 4);
    int* csrs = (int*)alloc((size_t)(E + N) * 4);
    short* w1bf = (short*)alloc(32768 * 2);
    float* b1p = (float*)alloc(128 * 4);
    float* w2t = (float*)alloc(40 * 128 * 4);
    u32* hbf8 = (u32*)alloc((size_t)N * 32 * 4);     // fp8 h, sigma-permuted (12.8MB)
    u32* staging = (u32*)alloc((size_t)(E + N) * 4); // bucket-sorted edge words (6.8MB)
    u32* h2q = hbf8;   // int8 h2 rows (6.4MB) alias hbf8 (dead after agg1g2's gathers...)
    // NOTE: h2q aliases hbf8 — but agg1g2 READS hbf8 while WRITING h2q!  -> give h2q its own space
    h2q = (u32*)alloc((size_t)N * 16 * 4);           // 6.4MB, no alias

    const int nblk = (E + EPB - 1) / EPB;
    const int g1blk = (N + 63) / 64;

    (void)hipMemsetAsync(gcnt, 0, (size_t)NB * 4, stream);
    k_pre<<<nblk + 128 + 21, 256, 0, stream>>>(ei, E, N, NB, nblk, gcnt, w1, w1bf,
                                               b1, w2, b1p, w2t);
    k_bscan<<<1, 512, 0, stream>>>(gcnt, ebase, cursor, off, NB, N);
    k_scatg1<<<nblk + g1blk, 256, 0, stream>>>(ei, cursor, staging, E, N, NB, nblk,
                                               x, w1bf, hbf8);
    k_build<<<NB, 256, 0, stream>>>(staging, ebase, csrs, off, dinv, N);
    k_agg1g2<<<(N + 7) / 8, 256, 0, stream>>>(hbf8, off, csrs, dinv, b1p, w2t,
                                              h2q, scl, N);
    k_agg2<<<(N + 3) / 4, 256, 0, stream>>>(h2q, scl, off, csrs, dinv, b2, out, N);
}

// Round 15
// 236.759 us; speedup vs baseline: 1.6717x; 1.6717x over previous
//
#include <hip/hip_runtime.h>
#include <hip/hip_bf16.h>
#include <math.h>
#include <stdint.h>

typedef unsigned short u16;
typedef unsigned int u32;
typedef __attribute__((ext_vector_type(8))) short short8;
typedef __attribute__((ext_vector_type(4))) float f32x4;
typedef __attribute__((ext_vector_type(2))) float f32x2;

#define BN 256      // nodes per bucket (power of 2)
#define NBMAX 400   // max buckets (N<=102400)
#define EPB 4096    // edges per block in count/scatter
#define ST1 160     // staged edges per node, agg1
#define ST2 192     // staged edges per node, agg2

__device__ __forceinline__ u16 bfbits(float f) {
    __hip_bfloat16 h = __float2bfloat16(f);
    return *reinterpret_cast<u16*>(&h);
}
__device__ __forceinline__ float bflo(u32 v) { return __uint_as_float(v << 16); }
__device__ __forceinline__ float bfhi(u32 v) { return __uint_as_float(v & 0xffff0000u); }

template <bool HI>
__device__ __forceinline__ f32x2 fp8pair(u32 v) {
#if __has_builtin(__builtin_amdgcn_cvt_pk_f32_fp8)
    return __builtin_amdgcn_cvt_pk_f32_fp8(v, HI);
#else
    f32x2 r;
    r.x = __builtin_amdgcn_cvt_f32_fp8(v, HI ? 2 : 0);
    r.y = __builtin_amdgcn_cvt_f32_fp8(v, HI ? 3 : 1);
    return r;
#endif
}

__device__ __forceinline__ int sigma128(int col) {
    int a = col >> 6, c = (col >> 4) & 3, lr = col & 15;
    return (a << 6) + (lr << 2) + c;
}

// ---------------- FUSED: bucket counts | W1->bf16 swizzle | b1/W2 sigma prep ----------------
__global__ __launch_bounds__(256) void k_pre(const int* __restrict__ ei, int E, int n, int nb,
                                             int nblkc, int* __restrict__ gcnt,
                                             const float* __restrict__ w1, short* __restrict__ w1bf,
                                             const float* __restrict__ b1, const float* __restrict__ w2,
                                             float* __restrict__ b1p, float* __restrict__ w2p) {
    __shared__ int sh[NBMAX];
    const int t = threadIdx.x;
    const int b = blockIdx.x;
    if (b < nblkc) {                           // ---- bucket count ----
        const int* col = ei + E;
        for (int i = t; i < nb; i += 256) sh[i] = 0;
        __syncthreads();
        const int base = b * EPB;
#pragma unroll
        for (int j = 0; j < 16; ++j) {
            int e = base + j * 256 + t;
            if (e < E) {
                unsigned c = (unsigned)col[e];
                if (c < (unsigned)n) atomicAdd(&sh[c >> 8], 1);
            }
        }
        __syncthreads();
        for (int i = t; i < nb; i += 256)
            if (sh[i]) atomicAdd(&gcnt[i], sh[i]);
    } else if (b < nblkc + 128) {              // ---- W1 swizzle (32768 elems) ----
        int i = (b - nblkc) * 256 + t;
        int e = i & 7, l = (i >> 3) & 63, kt = (i >> 9) & 7, ct = i >> 12;
        int k = kt * 32 + (l >> 4) * 8 + e;
        int c = ct * 16 + (l & 15);
        w1bf[i] = (short)bfbits(w1[(size_t)k * 128 + c]);
    } else {                                   // ---- b1/W2 sigma permute ----
        int i = (b - nblkc - 128) * 256 + t;
        if (i < 128) b1p[sigma128(i)] = b1[i];
        int j = i - 128;
        if (j >= 0 && j < 128 * 40) {
            int col = j / 40, jj = j - col * 40;
            w2p[sigma128(col) * 40 + jj] = w2[j];
        }
    }
}

// ---------------- bucket scan (single block) ----------------
__global__ __launch_bounds__(512) void k_bscan(const int* __restrict__ gcnt,
                                               int* __restrict__ ebase, int* __restrict__ cursor,
                                               int* __restrict__ off, int nb, int n) {
    __shared__ int sh[512];
    const int t = threadIdx.x;
    int v = (t < nb) ? gcnt[t] : 0;
    sh[t] = v;
    __syncthreads();
    for (int d = 1; d < 512; d <<= 1) {
        int x = (t >= d) ? sh[t - d] : 0;
        __syncthreads();
        sh[t] += x;
        __syncthreads();
    }
    if (t < nb) {
        int excl = sh[t] - v;
        ebase[t] = excl;
        cursor[t] = excl;
    }
    if (t == 0) {
        ebase[nb] = sh[511];
        off[n] = sh[511] + n;
    }
}

// ---------------- FUSED: edge scatter | GEMM1 (LDS-staged x, streaming loads) ----------------
struct SMemScat { int cnt[NBMAX]; int cbase[NBMAX]; };
union SMemU {
    SMemScat s;
    u16 xt[64 * 128];   // 16KB: 64 rows x 128 bf16 (one k-half), XOR-swizzled
};

__global__ __launch_bounds__(256) void k_scatg1(const int* __restrict__ ei,
                                                int* __restrict__ cursor, u32* __restrict__ staging,
                                                int E, int n, int nb, int nblks,
                                                const float* __restrict__ x,
                                                const short* __restrict__ w1bf,
                                                u32* __restrict__ hbf8) {
    __shared__ SMemU sm;
    const int t = threadIdx.x;
    if ((int)blockIdx.x < nblks) {             // ---- scat ----
        for (int i = t; i < nb; i += 256) sm.s.cnt[i] = 0;
        __syncthreads();
        const int base = blockIdx.x * EPB;
        int rr[16], cc[16], rk[16];
#pragma unroll
        for (int j = 0; j < 16; ++j) {
            int e = base + j * 256 + t;
            cc[j] = -1;
            if (e < E) {
                unsigned r = (unsigned)ei[e], c = (unsigned)ei[E + e];
                if (r < (unsigned)n && c < (unsigned)n) {
                    rr[j] = (int)r;
                    cc[j] = (int)c;
                    rk[j] = atomicAdd(&sm.s.cnt[c >> 8], 1);
                }
            }
        }
        __syncthreads();
        for (int i = t; i < nb; i += 256)
            if (sm.s.cnt[i]) sm.s.cbase[i] = atomicAdd(&cursor[i], sm.s.cnt[i]);
        __syncthreads();
#pragma unroll
        for (int j = 0; j < 16; ++j) {
            if (cc[j] >= 0) {
                int b = cc[j] >> 8;
                staging[sm.s.cbase[b] + rk[j]] = (u32)rr[j] | ((u32)(cc[j] & (BN - 1)) << 17);
            }
        }
        return;
    }
    // ---- gemm1: stage x -> LDS (bf16, swizzled) in 2 k-halves; frags via ds_read ----
    const int bid = blockIdx.x - nblks;
    const int wv = t >> 6, l = t & 63;
    const int mrow = wv >> 1, mcol = wv & 1;
    const int lr = l & 15, kg = l >> 4;
    const int n0 = bid * 64;

    const short* bbase = w1bf + ((size_t)(4 * mcol) * 8) * 64 * 8 + (size_t)l * 8;

    f32x4 zero = {0.f, 0.f, 0.f, 0.f};
    f32x4 acc[2][4];
#pragma unroll
    for (int m = 0; m < 2; ++m)
#pragma unroll
        for (int c = 0; c < 4; ++c) acc[m][c] = zero;

#pragma unroll
    for (int p = 0; p < 2; ++p) {
        __syncthreads();
#pragma unroll
        for (int j = 0; j < 8; ++j) {
            int idx = j * 256 + t;
            int row = idx >> 5;
            int kf4 = idx & 31;
            int grow = n0 + row;
            if (grow > n - 1) grow = n - 1;
            float4 v = *(const float4*)(x + (size_t)grow * 256 + p * 128 + kf4 * 4);
            u32 w0 = (u32)bfbits(v.x) | ((u32)bfbits(v.y) << 16);
            u32 w1v = (u32)bfbits(v.z) | ((u32)bfbits(v.w) << 16);
            int bir = kf4 * 8;
            int sb = row * 256 + (bir ^ ((row & 7) << 4));
            *(uint2*)((char*)sm.xt + sb) = make_uint2(w0, w1v);
        }
        __syncthreads();
#pragma unroll
        for (int ktl = 0; ktl < 4; ++ktl) {
            int kt = p * 4 + ktl;
            short8 af[2];
#pragma unroll
            for (int m = 0; m < 2; ++m) {
                int r = 32 * mrow + 16 * m + lr;
                int bir = ktl * 64 + kg * 16;
                int sb = r * 256 + (bir ^ ((r & 7) << 4));
                af[m] = *(const short8*)((const char*)sm.xt + sb);
            }
#pragma unroll
            for (int c = 0; c < 4; ++c) {
                short8 bfrag = *(const short8*)(bbase + ((size_t)(c * 8 + kt) * 64) * 8);
#pragma unroll
                for (int m = 0; m < 2; ++m)
                    acc[m][c] = __builtin_amdgcn_mfma_f32_16x16x32_bf16(af[m], bfrag,
                                                                        acc[m][c], 0, 0, 0);
            }
        }
    }

#pragma unroll
    for (int m = 0; m < 2; ++m) {
        int rbase = n0 + 32 * mrow + 16 * m + kg * 4;
#pragma unroll
        for (int r = 0; r < 4; ++r) {
            int row = rbase + r;
            if (row < n) {
                int w = __builtin_amdgcn_cvt_pk_fp8_f32(acc[m][0][r], acc[m][1][r], 0, false);
                w = __builtin_amdgcn_cvt_pk_fp8_f32(acc[m][2][r], acc[m][3][r], w, true);
                hbf8[(size_t)row * 32 + 16 * mcol + lr] = (u32)w;
            }
        }
    }
}

// ---------------- per-bucket CSR build ----------------
__global__ __launch_bounds__(256) void k_build(const u32* __restrict__ staging,
                                               const int* __restrict__ ebase,
                                               int* __restrict__ csrs, int* __restrict__ off,
                                               float* __restrict__ dinv, int n) {
    __shared__ int sh[256];
    __shared__ int cur[256];
    const int t = threadIdx.x;
    const int b = blockIdx.x;
    const int e0 = ebase[b], e1 = ebase[b + 1];
    const int node0 = b * BN;
    const int nn = min(BN, n - node0);
    sh[t] = 0;
    __syncthreads();
    for (int i = e0 + t; i < e1; i += 256)
        atomicAdd(&sh[staging[i] >> 17], 1);
    __syncthreads();
    const int mycnt = sh[t];
    const int myval = (t < nn) ? mycnt + 1 : 0;
    sh[t] = myval;
    __syncthreads();
    for (int d = 1; d < 256; d <<= 1) {
        int x = (t >= d) ? sh[t - d] : 0;
        __syncthreads();
        sh[t] += x;
        __syncthreads();
    }
    const int excl = sh[t] - myval;
    const int csrbase = e0 + node0;
    if (t < nn) {
        int node = node0 + t;
        int o = csrbase + excl;
        off[node] = o;
        dinv[node] = rsqrtf((float)(mycnt + 1));
        csrs[o] = node;
        cur[t] = o + 1;
    }
    __syncthreads();
    for (int i = e0 + t; i < e1; i += 256) {
        u32 v = staging[i];
        int p = atomicAdd(&cur[v >> 17], 1);
        csrs[p] = (int)(v & 0x1FFFF);
    }
}

// ---------------- Agg1: 2 nodes/wave, 32 lanes/node, u32 fp8 loads, unroll 16 ----------------
__global__ __launch_bounds__(256) void k_agg1(const u32* __restrict__ hbf8,
                                              const int* __restrict__ off,
                                              const int* __restrict__ csrs,
                                              const float* __restrict__ dinv,
                                              const float* __restrict__ b1p,
                                              u16* __restrict__ h1b, int n) {
    __shared__ int s_s[8][ST1];
    __shared__ float s_f[8][ST1];
    const int t = threadIdx.x, h = t >> 5, fl = t & 31;
    const int node = blockIdx.x * 8 + h;
    const int nd = node < n ? node : n - 1;
    const float dn = dinv[nd];
    const int e0 = off[nd], e1 = off[nd + 1];
    const int deg = e1 - e0;
    const int nst = deg < ST1 ? deg : ST1;
    for (int i = fl; i < nst; i += 32) {
        int s = csrs[e0 + i];
        s_s[h][i] = s;
        s_f[h][i] = dinv[s] * dn;
    }
    __syncthreads();

    const int onst = __shfl_xor(nst, 32, 64);
    const int nmin = nst < onst ? nst : onst;
    const int nmax = nst > onst ? nst : onst;
    const int odeg = __shfl_xor(deg, 32, 64);
    const int dmax = deg > odeg ? deg : odeg;

    const u32* hb = hbf8;
    float a0 = 0.f, a1 = 0.f, a2 = 0.f, a3 = 0.f;
    int i = 0;
    for (; i + 16 <= nmin; i += 16) {
        u32 vv[16];
        float ww[16];
#pragma unroll
        for (int k = 0; k < 16; ++k) {
            int s = s_s[h][i + k];
            ww[k] = s_f[h][i + k];
            vv[k] = hb[(size_t)s * 32 + fl];
        }
#pragma unroll
        for (int k = 0; k < 16; ++k) {
            f32x2 lo = fp8pair<false>(vv[k]), hi = fp8pair<true>(vv[k]);
            a0 = fmaf(lo.x, ww[k], a0); a1 = fmaf(lo.y, ww[k], a1);
            a2 = fmaf(hi.x, ww[k], a2); a3 = fmaf(hi.y, ww[k], a3);
        }
    }
    for (; i + 4 <= nmin; i += 4) {
        u32 vv[4];
        float ww[4];
#pragma unroll
        for (int k = 0; k < 4; ++k) {
            int s = s_s[h][i + k];
            ww[k] = s_f[h][i + k];
            vv[k] = hb[(size_t)s * 32 + fl];
        }
#pragma unroll
        for (int k = 0; k < 4; ++k) {
            f32x2 lo = fp8pair<false>(vv[k]), hi = fp8pair<true>(vv[k]);
            a0 = fmaf(lo.x, ww[k], a0); a1 = fmaf(lo.y, ww[k], a1);
            a2 = fmaf(hi.x, ww[k], a2); a3 = fmaf(hi.y, ww[k], a3);
        }
    }
    for (; i < nmin; ++i) {
        int s = s_s[h][i];
        float w = s_f[h][i];
        u32 v = hb[(size_t)s * 32 + fl];
        f32x2 lo = fp8pair<false>(v), hi = fp8pair<true>(v);
        a0 = fmaf(lo.x, w, a0); a1 = fmaf(lo.y, w, a1);
        a2 = fmaf(hi.x, w, a2); a3 = fmaf(hi.y, w, a3);
    }
    for (; i < nmax; ++i) {
        bool ok = i < nst;
        int s = ok ? s_s[h][i] : nd;
        float w = ok ? s_f[h][i] : 0.f;
        u32 v = hb[(size_t)s * 32 + fl];
        f32x2 lo = fp8pair<false>(v), hi = fp8pair<true>(v);
        a0 = fmaf(lo.x, w, a0); a1 = fmaf(lo.y, w, a1);
        a2 = fmaf(hi.x, w, a2); a3 = fmaf(hi.y, w, a3);
    }
    for (int j = ST1; j < dmax; ++j) {
        bool ok = j < deg;
        int s = ok ? csrs[e0 + j] : nd;
        float w = ok ? dinv[s] * dn : 0.f;
        u32 v = hb[(size_t)s * 32 + fl];
        f32x2 lo = fp8pair<false>(v), hi = fp8pair<true>(v);
        a0 = fmaf(lo.x, w, a0); a1 = fmaf(lo.y, w, a1);
        a2 = fmaf(hi.x, w, a2); a3 = fmaf(hi.y, w, a3);
    }

    float4 bb = *(const float4*)(b1p + 4 * fl);
    float r0 = fmaxf(a0 + bb.x, 0.f);
    float r1 = fmaxf(a1 + bb.y, 0.f);
    float r2 = fmaxf(a2 + bb.z, 0.f);
    float r3 = fmaxf(a3 + bb.w, 0.f);
    if (node < n) {
        uint2 o;
        o.x = (u32)bfbits(r0) | ((u32)bfbits(r1) << 16);
        o.y = (u32)bfbits(r2) | ((u32)bfbits(r3) << 16);
        ((uint2*)h1b)[(size_t)node * 32 + fl] = o;
    }
}

// ---------------- GEMM2: h2 = h1 @ W2p -> int8 (64B rows) + per-node scale ----------------
__global__ __launch_bounds__(64) void k_gemm2(const u16* __restrict__ h1b,
                                              const float* __restrict__ w2p,
                                              u32* __restrict__ h2q, float* __restrict__ scl,
                                              int n) {
    __shared__ float hs[64 * 132];
    const int t = threadIdx.x;
    const int n0 = blockIdx.x * 64;
    const uint4* src = (const uint4*)(h1b + (size_t)n0 * 128);
#pragma unroll
    for (int i = 0; i < 16; ++i) {
        int idx = i * 64 + t;
        int r = idx >> 4, q = idx & 15;
        uint4 v = make_uint4(0u, 0u, 0u, 0u);
        if (n0 + r < n) v = src[(size_t)r * 16 + q];
        *(float4*)&hs[r * 132 + q * 8] =
            make_float4(bflo(v.x), bfhi(v.x), bflo(v.y), bfhi(v.y));
        *(float4*)&hs[r * 132 + q * 8 + 4] =
            make_float4(bflo(v.z), bfhi(v.z), bflo(v.w), bfhi(v.w));
    }
    __syncthreads();

    float acc[40];
#pragma unroll
    for (int c = 0; c < 40; ++c) acc[c] = 0.f;

    for (int k4 = 0; k4 < 32; ++k4) {
        float4 hv = *(const float4*)&hs[t * 132 + 4 * k4];
#pragma unroll
        for (int j = 0; j < 4; ++j) {
            float xv = (j == 0) ? hv.x : (j == 1) ? hv.y : (j == 2) ? hv.z : hv.w;
            const float* wr = w2p + (size_t)(4 * k4 + j) * 40;   // wave-uniform -> s_load
#pragma unroll
            for (int c = 0; c < 40; ++c) acc[c] = fmaf(xv, wr[c], acc[c]);
        }
    }
    __syncthreads();

    float mx = 0.f;
#pragma unroll
    for (int c = 0; c < 40; ++c) mx = fmaxf(mx, fabsf(acc[c]));
    const float qs = mx > 0.f ? 127.f / mx : 0.f;
    u32* rowp = (u32*)hs + t * 16;
#pragma unroll
    for (int j = 0; j < 10; ++j) {
        u32 w = 0;
#pragma unroll
        for (int k = 0; k < 4; ++k) {
            int q = __float2int_rn(acc[4 * j + k] * qs);
            q = q > 127 ? 127 : (q < -127 ? -127 : q);
            w |= ((u32)(q & 255)) << (8 * k);
        }
        rowp[j] = w;
    }
#pragma unroll
    for (int j = 10; j < 16; ++j) rowp[j] = 0;
    __syncthreads();
    const int nrow = (n - n0 < 64) ? n - n0 : 64;
    uint4* dst = (uint4*)(h2q + (size_t)n0 * 16);
    const uint4* s4 = (const uint4*)hs;
#pragma unroll
    for (int i = 0; i < 4; ++i) {
        int idx = i * 64 + t;
        if ((idx >> 2) < nrow) dst[idx] = s4[idx];
    }
    if (t < nrow) scl[n0 + t] = mx * (1.f / 127.f);
}

// ---------------- Agg2 (int8 gather) + bias + log_softmax ----------------
__global__ __launch_bounds__(256) void k_agg2(const u32* __restrict__ h2q,
                                              const float* __restrict__ scl,
                                              const int* __restrict__ off,
                                              const int* __restrict__ csrs,
                                              const float* __restrict__ dinv,
                                              const float* __restrict__ b2,
                                              float* __restrict__ out, int n) {
    __shared__ int s_s[4][ST2];
    __shared__ float s_f[4][ST2];
    const int t = threadIdx.x, wv = t >> 6, l = t & 63;
    const int node = blockIdx.x * 4 + wv;
    const int nd = node < n ? node : n - 1;
    const float dn = dinv[nd];
    const int e0 = off[nd], e1 = off[nd + 1];
    const int deg = e1 - e0;
    const int nst = deg < ST2 ? deg : ST2;
    for (int i = l; i < nst; i += 64) {
        int s = csrs[e0 + i];
        s_s[wv][i] = s;
        s_f[wv][i] = dinv[s] * dn * scl[s];
    }
    __syncthreads();

    const int g = l >> 4;
    const int fl = l & 15;

#define ACC4(v, w)                                                         \
    {                                                                      \
        a0 = fmaf((float)(int)(signed char)((v) & 0xff), (w), a0);         \
        a1 = fmaf((float)(int)(signed char)(((v) >> 8) & 0xff), (w), a1);  \
        a2 = fmaf((float)(int)(signed char)(((v) >> 16) & 0xff), (w), a2); \
        a3 = fmaf((float)(int)(signed char)((v) >> 24), (w), a3);          \
    }

    float a0 = 0.f, a1 = 0.f, a2 = 0.f, a3 = 0.f;
    int base = 0;
    for (; base + 16 <= nst; base += 16) {
        int eA = base + g, eB = base + 4 + g, eC = base + 8 + g, eD = base + 12 + g;
        int sA = s_s[wv][eA], sB = s_s[wv][eB], sC = s_s[wv][eC], sD = s_s[wv][eD];
        float wA = s_f[wv][eA], wB = s_f[wv][eB], wC = s_f[wv][eC], wD = s_f[wv][eD];
        u32 vA = h2q[(size_t)sA * 16 + fl];
        u32 vB = h2q[(size_t)sB * 16 + fl];
        u32 vC = h2q[(size_t)sC * 16 + fl];
        u32 vD = h2q[(size_t)sD * 16 + fl];
        ACC4(vA, wA); ACC4(vB, wB); ACC4(vC, wC); ACC4(vD, wD);
    }
    for (; base < nst; base += 4) {
        int e = base + g;
        bool ok = e < nst;
        int s = ok ? s_s[wv][e] : nd;
        float w = ok ? s_f[wv][e] : 0.f;
        u32 v = h2q[(size_t)s * 16 + fl];
        ACC4(v, w);
    }
    for (int j = nst; j < deg; j += 4) {
        int e = j + g;
        bool ok = e < deg;
        int s = ok ? csrs[e0 + e] : nd;
        float w = ok ? dinv[s] * dn * scl[s] : 0.f;
        u32 v = h2q[(size_t)s * 16 + fl];
        ACC4(v, w);
    }
#undef ACC4

    float t0 = __shfl(a0, (l + 32) & 63, 64);
    float t1 = __shfl(a1, (l + 32) & 63, 64);
    float t2 = __shfl(a2, (l + 32) & 63, 64);
    float t3 = __shfl(a3, (l + 32) & 63, 64);
    a0 += t0; a1 += t1; a2 += t2; a3 += t3;
    t0 = __shfl(a0, (l + 16) & 63, 64);
    t1 = __shfl(a1, (l + 16) & 63, 64);
    t2 = __shfl(a2, (l + 16) & 63, 64);
    t3 = __shfl(a3, (l + 16) & 63, 64);
    a0 += t0; a1 += t1; a2 += t2; a3 += t3;

    const bool act = (l < 10);
    float4 bb = *(const float4*)(b2 + 4 * (act ? l : 9));
    float v0 = a0 + bb.x, v1 = a1 + bb.y, v2 = a2 + bb.z, v3 = a3 + bb.w;

    float m = act ? fmaxf(fmaxf(v0, v1), fmaxf(v2, v3)) : -INFINITY;
#pragma unroll
    for (int d = 8; d > 0; d >>= 1) m = fmaxf(m, __shfl_xor(m, d, 16));
    float s = act ? (__expf(v0 - m) + __expf(v1 - m) + __expf(v2 - m) + __expf(v3 - m)) : 0.f;
#pragma unroll
    for (int d = 8; d > 0; d >>= 1) s += __shfl_xor(s, d, 16);
    float ls = logf(s);
    if (node < n && act) {
        float4 o = make_float4(v0 - m - ls, v1 - m - ls, v2 - m - ls, v3 - m - ls);
        *(float4*)(out + (size_t)node * 40 + 4 * l) = o;
    }
}

extern "C" void kernel_launch(void* const* d_in, const int* in_sizes, int n_in,
                              void* d_out, int out_size, void* d_ws, size_t ws_size,
                              hipStream_t stream) {
    const float* x = (const float*)d_in[0];
    const int* ei = (const int*)d_in[1];
    const float* w1 = (const float*)d_in[2];
    const float* b1 = (const float*)d_in[3];
    const float* w2 = (const float*)d_in[4];
    const float* b2 = (const float*)d_in[5];
    float* out = (float*)d_out;

    const int N = in_sizes[0] / 256;
    const int E = in_sizes[1] / 2;
    const int NB = (N + BN - 1) / BN;

    char* p = (char*)d_ws;
    auto alloc = [&](size_t bytes) {
        char* r = p;
        p += (bytes + 255) & ~(size_t)255;
        return r;
    };
    int* gcnt = (int*)alloc((size_t)NB * 4);
    int* ebase = (int*)alloc((size_t)(NB + 1) * 4);
    int* cursor = (int*)alloc((size_t)NB * 4);
    int* off = (int*)alloc((size_t)(N + 1) * 4);
    float* dinv = (float*)alloc((size_t)N * 4);
    float* scl = (float*)alloc((size_t)N * 4);
    int* csrs = (int*)alloc((size_t)(E + N) * 4);
    short* w1bf = (short*)alloc(32768 * 2);
    float* b1p = (float*)alloc(128 * 4);
    float* w2p = (float*)alloc(128 * 40 * 4);
    u32* hbf8 = (u32*)alloc((size_t)N * 32 * 4);     // fp8 h, sigma-permuted (12.8MB)
    u16* h1b = (u16*)alloc((size_t)N * 128 * 2);     // bf16 h1 (25.6MB)
    u32* staging = (u32*)h1b;  // staging dead before agg1 writes h1b
    u32* h2q = hbf8;           // int8 h2 rows (6.4MB) alias hbf8 (dead after agg1)

    const int nblk = (E + EPB - 1) / EPB;
    const int g1blk = (N + 63) / 64;

    (void)hipMemsetAsync(gcnt, 0, (size_t)NB * 4, stream);
    k_pre<<<nblk + 128 + 21, 256, 0, stream>>>(ei, E, N, NB, nblk, gcnt, w1, w1bf,
                                               b1, w2, b1p, w2p);
    k_bscan<<<1, 512, 0, stream>>>(gcnt, ebase, cursor, off, NB, N);
    k_scatg1<<<nblk + g1blk, 256, 0, stream>>>(ei, cursor, staging, E, N, NB, nblk,
                                               x, w1bf, hbf8);
    k_build<<<NB, 256, 0, stream>>>(staging, ebase, csrs, off, dinv, N);
    k_agg1<<<(N + 7) / 8, 256, 0, stream>>>(hbf8, off, csrs, dinv, b1p, h1b, N);
    k_gemm2<<<g1blk, 64, 0, stream>>>(h1b, w2p, h2q, scl, N);
    k_agg2<<<(N + 3) / 4, 256, 0, stream>>>(h2q, scl, off, csrs, dinv, b2, out, N);
}